// Round 1
// baseline (687.301 us; speedup 1.0000x reference)
//
#include <hip/hip_runtime.h>
#include <hip/hip_fp16.h>

#define T_DIM 2048
#define B_DIM 16
#define D_DIM 1024
#define M_TOT (T_DIM * B_DIM)   // 32768
#define N_TOT (2 * D_DIM)       // 2048 (W_alpha rows then W_x rows)
#define K_TOT D_DIM             // 1024
#define BD    (B_DIM * D_DIM)   // 16384 chains

typedef __attribute__((ext_vector_type(8))) short short8;
typedef __attribute__((ext_vector_type(4))) float floatx4;

__device__ __forceinline__ short f32_to_bf16(float f) {
  unsigned u = __float_as_uint(f);
  u = (u + 0x7FFFu + ((u >> 16) & 1u)) >> 16;   // RNE
  return (short)u;
}

// ---------------- cast fp32 -> bf16, 8 elems/thread ----------------
__global__ __launch_bounds__(256) void cast_bf16_k(const float* __restrict__ src,
                                                   short* __restrict__ dst) {
  const size_t i = ((size_t)blockIdx.x * 256 + threadIdx.x) * 8;
  floatx4 f0 = *(const floatx4*)(src + i);
  floatx4 f1 = *(const floatx4*)(src + i + 4);
  short8 o;
  o[0] = f32_to_bf16(f0[0]); o[1] = f32_to_bf16(f0[1]);
  o[2] = f32_to_bf16(f0[2]); o[3] = f32_to_bf16(f0[3]);
  o[4] = f32_to_bf16(f1[0]); o[5] = f32_to_bf16(f1[1]);
  o[6] = f32_to_bf16(f1[2]); o[7] = f32_to_bf16(f1[3]);
  *(short8*)(dst + i) = o;
}

// ---------------- fused dual-GEMM + activation epilogue ----------------
// out[m,n] = sum_k xb[m,k]*wb[n,k]; n<1024 -> alpha=sigmoid(+b_alpha), else v_raw=tanh(+b_v)
// LDS bank-conflict fix: k-chunk column XOR-swizzled by perm(row)=(row&3)^((row>>2)&1).
// Staging permutes the GLOBAL source chunk per lane (LDS dest is HW-pinned to lane*16B;
// same 64B lines -> coalescing unchanged); fragment reads col = quad^perm -> 2-way (free).
#define GLDS16(gp, lp)                                                                   \
  __builtin_amdgcn_global_load_lds((const __attribute__((address_space(1))) void*)(gp),  \
                                   (__attribute__((address_space(3))) void*)(lp), 16, 0, 0)

__global__ __launch_bounds__(256, 2) void gemm_act_k(
    const short* __restrict__ xb, const short* __restrict__ wb,
    const float* __restrict__ b_alpha, const float* __restrict__ b_v,
    __half* __restrict__ pairbuf) {
  __shared__ __align__(16) short As[128 * 32];
  __shared__ __align__(16) short Bs[128 * 32];
  const int tid  = threadIdx.x;
  const int wave = tid >> 6;
  const int lane = tid & 63;
  const int quad = lane >> 4;
  const int l16  = lane & 15;
  const int mblk = blockIdx.y << 7;
  const int nblk = blockIdx.x << 7;
  const int wrow = (wave >> 1) << 6;
  const int wcol = (wave & 1) << 6;

  floatx4 acc[4][4];
#pragma unroll
  for (int i = 0; i < 4; ++i)
#pragma unroll
    for (int j = 0; j < 4; ++j) acc[i][j] = {0.f, 0.f, 0.f, 0.f};

  // staging: row = tid>>2 (instr1: +64), swizzled source k-chunk
  const int chunk_m = tid >> 2;   // 0..63
  const int c_swz   = (tid & 3) ^ (chunk_m & 3) ^ ((chunk_m >> 2) & 1);
  const short* gA0 = xb + (size_t)(mblk + chunk_m) * K_TOT + c_swz * 8;
  const short* gA1 = gA0 + (size_t)64 * K_TOT;
  const short* gB0 = wb + (size_t)(nblk + chunk_m) * K_TOT + c_swz * 8;
  const short* gB1 = gB0 + (size_t)64 * K_TOT;
  short* lA0 = As + wave * 512;
  short* lA1 = As + 2048 + wave * 512;
  short* lB0 = Bs + wave * 512;
  short* lB1 = Bs + 2048 + wave * 512;

  // fragment read: row = wrow/wcol + i*16 + l16; perm(row) == perm(l16) (base mult of 16)
  const int pl   = (l16 & 3) ^ ((l16 >> 2) & 1);
  const int aoff = (wrow + l16) * 32 + ((quad ^ pl) * 8);
  const int boff = (wcol + l16) * 32 + ((quad ^ pl) * 8);

  for (int k0 = 0; k0 < K_TOT; k0 += 32) {
    GLDS16(gA0 + k0, lA0);
    GLDS16(gA1 + k0, lA1);
    GLDS16(gB0 + k0, lB0);
    GLDS16(gB1 + k0, lB1);
    __syncthreads();
    short8 af[4], bf[4];
#pragma unroll
    for (int i = 0; i < 4; ++i) af[i] = *(const short8*)(As + aoff + i * 512);
#pragma unroll
    for (int i = 0; i < 4; ++i) bf[i] = *(const short8*)(Bs + boff + i * 512);
#pragma unroll
    for (int i = 0; i < 4; ++i)
#pragma unroll
      for (int j = 0; j < 4; ++j)
        acc[i][j] = __builtin_amdgcn_mfma_f32_16x16x32_bf16(af[i], bf[j], acc[i][j], 0, 0, 0);
    __syncthreads();
  }

  const bool isA = (nblk < D_DIM);          // block-uniform
  const float* __restrict__ bias = isA ? b_alpha : b_v;
  const int hsel = isA ? 0 : 1;
#pragma unroll
  for (int j = 0; j < 4; ++j) {
    const int n_g = nblk + wcol + j * 16 + l16;
    const int e = isA ? n_g : (n_g - D_DIM);
    const float bz = bias[e];
#pragma unroll
    for (int i = 0; i < 4; ++i) {
      const floatx4 v = acc[i][j];
      const int m_base = mblk + wrow + i * 16 + quad * 4;  // D: row = quad*4+reg, col = l16
#pragma unroll
      for (int r = 0; r < 4; ++r) {
        const float z = v[r] + bz;
        float val;
        if (isA) {
          val = __builtin_amdgcn_rcpf(1.f + __expf(-z));                   // sigmoid
        } else {
          val = 1.f - 2.f * __builtin_amdgcn_rcpf(__expf(2.f * z) + 1.f);  // tanh
        }
        pairbuf[((size_t)(m_base + r) * D_DIM + e) * 2 + hsel] = __float2half(val);
      }
    }
  }
}

// ---------------- fused sequential scan + silu epilogue, fp32 outputs ----------------
// Per 16-step group: (a) burst-issue 16 next-group loads at compile-time offsets
// (no serial address chain -> full MLP), (b) 16 recurrence steps in registers, with
// out = h^2*sigmoid(h) computed off the critical path, (c) burst 32 fp32 stores.
// Eliminates silu_k and the 64MB fp16 h write + 67MB re-read entirely.
__global__ __launch_bounds__(64) void scan_fused_k(const __half2* __restrict__ pair,
                                                   const float* __restrict__ d_g,
                                                   const float* __restrict__ b_g,
                                                   float* __restrict__ outbuf) {
  const int c = blockIdx.x * 64 + threadIdx.x;   // chain id = b*D + d
  const float LOG2E = 1.44269504f;
  const float dg = d_g[c & (D_DIM - 1)] * LOG2E;
  const float bg = b_g[c & (D_DIM - 1)] * LOG2E;
  float* __restrict__ outs = outbuf;                        // [T, B*D]
  float* __restrict__ hout = outbuf + (size_t)T_DIM * BD;   // [T+1, B*D]
  hout[c] = 0.f;                                            // h0 row
  float h = 0.f;

  __half2 pc[16], pn[16];
#pragma unroll
  for (int k = 0; k < 16; ++k) pc[k] = pair[(size_t)k * BD + c];   // group 0

  size_t sidx = c;   // outs row t, hout row t+1 = sidx + BD
  for (int t = 0; t < T_DIM; t += 16) {
    // (a) burst prefetch of next group (dummy in-bounds addr on last group)
    const bool more = (t + 16 < T_DIM);
    const size_t lbase = more ? ((size_t)(t + 16) * BD + c) : (size_t)c;
    const size_t lstep = more ? (size_t)BD : 0;
#pragma unroll
    for (int k = 0; k < 16; ++k) pn[k] = pair[lbase + (size_t)k * lstep];

    // (b) 16 recurrence steps, all in registers
    float hv[16], ov[16];
#pragma unroll
    for (int k = 0; k < 16; ++k) {
      const float2 av = __half22float2(pc[k]);   // .x = alpha, .y = v_raw
      const float w = (1.f - av.x) * av.y;       // off critical path
      const float e = __builtin_amdgcn_exp2f(fmaf(dg, fabsf(h), -bg));
      const float g = __builtin_amdgcn_rcpf(1.f + e);
      h = fmaf(av.x, h, w * g);                  // alpha*h + (1-alpha)*v*g
      hv[k] = h;
      const float s = __builtin_amdgcn_rcpf(1.f + __builtin_amdgcn_exp2f(-LOG2E * h));
      ov[k] = h * (h * s);                       // h * silu(h), off critical path
    }

    // (c) burst stores: out[t+k] and h[t+k+1], fp32
#pragma unroll
    for (int k = 0; k < 16; ++k) {
      outs[sidx + (size_t)k * BD] = ov[k];
      hout[sidx + (size_t)k * BD + BD] = hv[k];
    }
    sidx += (size_t)16 * BD;

#pragma unroll
    for (int k = 0; k < 16; ++k) pc[k] = pn[k];
  }
}

extern "C" void kernel_launch(void* const* d_in, const int* in_sizes, int n_in,
                              void* d_out, int out_size, void* d_ws, size_t ws_size,
                              hipStream_t stream) {
  const float* x       = (const float*)d_in[0];
  const float* W_alpha = (const float*)d_in[1];
  const float* b_alpha = (const float*)d_in[2];
  const float* d_g     = (const float*)d_in[3];
  const float* b_g     = (const float*)d_in[4];
  const float* W_x     = (const float*)d_in[5];
  const float* b_v     = (const float*)d_in[6];
  float* out = (float*)d_out;

  // ws layout: xb (64MB) | wb (4MB) | pairbuf (128MB)
  char* ws = (char*)d_ws;
  short*  xb      = (short*)ws;                                  // [32768][1024] bf16
  short*  wb      = (short*)(ws + (size_t)67108864);             // [2048][1024] bf16
  __half* pairbuf = (__half*)(ws + (size_t)71303168);            // [32768][1024][2] fp16

  cast_bf16_k<<<M_TOT * K_TOT / (8 * 256), 256, 0, stream>>>(x, xb);
  cast_bf16_k<<<D_DIM * K_TOT / (8 * 256), 256, 0, stream>>>(W_alpha, wb);
  cast_bf16_k<<<D_DIM * K_TOT / (8 * 256), 256, 0, stream>>>(W_x, wb + (size_t)D_DIM * K_TOT);
  gemm_act_k<<<dim3(N_TOT / 128, M_TOT / 128), 256, 0, stream>>>(xb, wb, b_alpha, b_v, pairbuf);
  scan_fused_k<<<BD / 64, 64, 0, stream>>>((const __half2*)pairbuf, d_g, b_g, out);
}

// Round 2
// 684.466 us; speedup vs baseline: 1.0041x; 1.0041x over previous
//
#include <hip/hip_runtime.h>
#include <hip/hip_fp16.h>

#define T_DIM 2048
#define B_DIM 16
#define D_DIM 1024
#define M_TOT (T_DIM * B_DIM)   // 32768
#define N_TOT (2 * D_DIM)       // 2048 (W_alpha rows then W_x rows)
#define K_TOT D_DIM             // 1024
#define BD    (B_DIM * D_DIM)   // 16384 chains

typedef __attribute__((ext_vector_type(8))) short short8;
typedef __attribute__((ext_vector_type(4))) float floatx4;

__device__ __forceinline__ short f32_to_bf16(float f) {
  unsigned u = __float_as_uint(f);
  u = (u + 0x7FFFu + ((u >> 16) & 1u)) >> 16;   // RNE
  return (short)u;
}

// ---------------- cast fp32 -> bf16, 8 elems/thread ----------------
__global__ __launch_bounds__(256) void cast_bf16_k(const float* __restrict__ src,
                                                   short* __restrict__ dst) {
  const size_t i = ((size_t)blockIdx.x * 256 + threadIdx.x) * 8;
  floatx4 f0 = *(const floatx4*)(src + i);
  floatx4 f1 = *(const floatx4*)(src + i + 4);
  short8 o;
  o[0] = f32_to_bf16(f0[0]); o[1] = f32_to_bf16(f0[1]);
  o[2] = f32_to_bf16(f0[2]); o[3] = f32_to_bf16(f0[3]);
  o[4] = f32_to_bf16(f1[0]); o[5] = f32_to_bf16(f1[1]);
  o[6] = f32_to_bf16(f1[2]); o[7] = f32_to_bf16(f1[3]);
  *(short8*)(dst + i) = o;
}

// ---------------- fused dual-GEMM + activation epilogue ----------------
// 256x256 tile, BK=32, 8 waves (2M x 4N), 4-deep circular LDS pipeline (128 KiB).
// Staging runs 3 K-tiles ahead; per-tile wait is vmcnt(8) (counts loads of the 2
// newer tiles still in flight) -> the drained tile's loads were issued 3 iters ago,
// so the wait is near-free. One raw s_barrier per K-tile (no vmcnt(0) drain).
// k-chunk XOR swizzle identical to the verified 128^2 kernel: perm(row)=(row&3)^((row>>2)&1);
// staging fetches global chunk (tid&3)^perm(row) into position tid&3; fragment reads
// position quad^perm(l16) -> 2-way LDS bank aliasing (free).
#define GLDS16(gp, lp)                                                                   \
  __builtin_amdgcn_global_load_lds((const __attribute__((address_space(1))) void*)(gp),  \
                                   (__attribute__((address_space(3))) void*)(lp), 16, 0, 0)

__global__ __launch_bounds__(512, 2) void gemm_act_k(
    const short* __restrict__ xb, const short* __restrict__ wb,
    const float* __restrict__ b_alpha, const float* __restrict__ b_v,
    __half* __restrict__ pairbuf) {
  // A slots: [4][256 rows][32 k] bf16 = 4 x 16KB at smem + s*8192 (shorts)
  // B slots: same, at smem + 32768 + s*8192
  __shared__ __align__(16) short smem[65536];   // 128 KiB
  const int tid  = threadIdx.x;
  const int wave = tid >> 6;        // 0..7
  const int lane = tid & 63;
  const int quad = lane >> 4;
  const int l16  = lane & 15;
  const int wm   = wave >> 2;       // 0..1  (M half)
  const int wn   = wave & 3;        // 0..3  (N quarter)
  const int nblk = blockIdx.x << 8; // grid.x = 8  -> XCD gets one n-stripe (B slice L2-resident)
  const int mblk = blockIdx.y << 8; // grid.y = 128

  floatx4 acc[8][4];
#pragma unroll
  for (int i = 0; i < 8; ++i)
#pragma unroll
    for (int j = 0; j < 4; ++j) acc[i][j] = {0.f, 0.f, 0.f, 0.f};

  // staging: thread -> row tid>>2 (and +128), stored chunk tid&3, swizzled source chunk
  const int rowA  = tid >> 2;                                  // 0..127
  const int c_swz = (tid & 3) ^ (rowA & 3) ^ ((rowA >> 2) & 1);
  const short* gA0 = xb + (size_t)(mblk + rowA) * K_TOT + c_swz * 8;
  const short* gA1 = gA0 + (size_t)128 * K_TOT;
  const short* gB0 = wb + (size_t)(nblk + rowA) * K_TOT + c_swz * 8;
  const short* gB1 = gB0 + (size_t)128 * K_TOT;

#define STAGE(s_, k0_) do {                                   \
    short* aA = smem + (s_) * 8192 + wave * 512;              \
    short* aB = smem + 32768 + (s_) * 8192 + wave * 512;      \
    GLDS16(gA0 + (k0_), aA);                                  \
    GLDS16(gA1 + (k0_), aA + 4096);                           \
    GLDS16(gB0 + (k0_), aB);                                  \
    GLDS16(gB1 + (k0_), aB + 4096);                           \
  } while (0)

  // fragment read offsets (shorts): row stride 32, chunk = quad ^ perm(l16)
  const int pl   = (l16 & 3) ^ ((l16 >> 2) & 1);
  const int aoff = (wm * 128 + l16) * 32 + ((quad ^ pl) * 8);
  const int boff = 32768 + (wn * 64 + l16) * 32 + ((quad ^ pl) * 8);

  // prologue: stage tiles 0,1,2 -> 12 loads; drain tile 0's four
  STAGE(0, 0);
  STAGE(1, 32);
  STAGE(2, 64);
  asm volatile("s_waitcnt vmcnt(8)" ::: "memory");
  __builtin_amdgcn_sched_barrier(0);
  __builtin_amdgcn_s_barrier();
  __builtin_amdgcn_sched_barrier(0);

  for (int t = 0; t < 32; ++t) {
    const int s = t & 3;
    const int k0n = (t < 29) ? (t + 3) * 32 : 0;   // tail: restage tile 0 into dead slot
    STAGE((t + 3) & 3, k0n);

    const short* sb = smem + s * 8192;
    short8 af[8], bf[4];
#pragma unroll
    for (int i = 0; i < 8; ++i) af[i] = *(const short8*)(sb + aoff + i * 512);
#pragma unroll
    for (int j = 0; j < 4; ++j) bf[j] = *(const short8*)(sb + boff + j * 512);

    __builtin_amdgcn_s_setprio(1);
#pragma unroll
    for (int i = 0; i < 8; ++i)
#pragma unroll
      for (int j = 0; j < 4; ++j)
        acc[i][j] = __builtin_amdgcn_mfma_f32_16x16x32_bf16(af[i], bf[j], acc[i][j], 0, 0, 0);
    __builtin_amdgcn_s_setprio(0);

    asm volatile("s_waitcnt lgkmcnt(0)" ::: "memory");    // own ds_reads done (no-op by now)
    __builtin_amdgcn_sched_barrier(0);
    asm volatile("s_waitcnt vmcnt(8)" ::: "memory");      // drain loads for tile t+1 only
    __builtin_amdgcn_sched_barrier(0);
    __builtin_amdgcn_s_barrier();
    __builtin_amdgcn_sched_barrier(0);
  }

  const bool isA = (nblk < D_DIM);          // block-uniform (BN=256 divides D)
  const float* __restrict__ bias = isA ? b_alpha : b_v;
  const int hsel = isA ? 0 : 1;
#pragma unroll
  for (int j = 0; j < 4; ++j) {
    const int n_g = nblk + wn * 64 + j * 16 + l16;
    const int e = isA ? n_g : (n_g - D_DIM);
    const float bz = bias[e];
#pragma unroll
    for (int i = 0; i < 8; ++i) {
      const floatx4 v = acc[i][j];
      const int m_base = mblk + wm * 128 + i * 16 + quad * 4;  // D: row = quad*4+reg, col = l16
#pragma unroll
      for (int r = 0; r < 4; ++r) {
        const float z = v[r] + bz;
        float val;
        if (isA) {
          val = __builtin_amdgcn_rcpf(1.f + __expf(-z));                   // sigmoid
        } else {
          val = 1.f - 2.f * __builtin_amdgcn_rcpf(__expf(2.f * z) + 1.f);  // tanh
        }
        pairbuf[((size_t)(m_base + r) * D_DIM + e) * 2 + hsel] = __float2half(val);
      }
    }
  }
#undef STAGE
}

// ---------------- sequential scan: h-recurrence only, fp16 h out ----------------
// Group-burst structure (verified round 1) with 32-deep prefetch (2 groups in flight)
// and compact fp16 h stores; fp32 expansion stays in high-occupancy silu_k.
__global__ __launch_bounds__(64) void scan_k(const __half2* __restrict__ pair,
                                             const float* __restrict__ d_g,
                                             const float* __restrict__ b_g,
                                             __half* __restrict__ hh) {
  const int c = blockIdx.x * 64 + threadIdx.x;   // chain id = b*D + d
  const float LOG2E = 1.44269504f;
  const float dg = d_g[c & (D_DIM - 1)] * LOG2E;
  const float bg = b_g[c & (D_DIM - 1)] * LOG2E;
  hh[c] = __float2half(0.f);                     // h0
  float h = 0.f;

  __half2 pc[16], pn[16], pf[16];
#pragma unroll
  for (int k = 0; k < 16; ++k) pc[k] = pair[(size_t)k * BD + c];
#pragma unroll
  for (int k = 0; k < 16; ++k) pn[k] = pair[(size_t)(k + 16) * BD + c];

  size_t sidx = c;
  for (int t = 0; t < T_DIM; t += 16) {
    const bool more = (t + 32 < T_DIM);
    const size_t lbase = more ? ((size_t)(t + 32) * BD + c) : (size_t)c;
    const size_t lstep = more ? (size_t)BD : 0;
#pragma unroll
    for (int k = 0; k < 16; ++k) pf[k] = pair[lbase + (size_t)k * lstep];

#pragma unroll
    for (int k = 0; k < 16; ++k) {
      const float2 av = __half22float2(pc[k]);   // .x = alpha, .y = v_raw
      const float w = (1.f - av.x) * av.y;       // off critical path
      const float e = __builtin_amdgcn_exp2f(fmaf(dg, fabsf(h), -bg));
      const float g = __builtin_amdgcn_rcpf(1.f + e);
      h = fmaf(av.x, h, w * g);                  // alpha*h + (1-alpha)*v*g
      hh[sidx + (size_t)k * BD + BD] = __float2half(h);
    }
    sidx += (size_t)16 * BD;

#pragma unroll
    for (int k = 0; k < 16; ++k) pc[k] = pn[k];
#pragma unroll
    for (int k = 0; k < 16; ++k) pn[k] = pf[k];
  }
}

// ---------------- parallel epilogue: expand h fp16->fp32, out = h^2 * sigmoid(h) ----
__global__ __launch_bounds__(256) void silu_k(const __half* __restrict__ hh,
                                              float* __restrict__ outbuf) {
  const float LOG2E = 1.44269504f;
  const size_t i = ((size_t)blockIdx.x * 256 + threadIdx.x) * 8;  // i < (T+1)*BD
  float* __restrict__ outs = outbuf;                       // [T, B*D]
  float* __restrict__ hout = outbuf + (size_t)T_DIM * BD;  // [T+1, B*D]
  const __half2* hp = (const __half2*)(hh + i);
  float hf[8];
#pragma unroll
  for (int j = 0; j < 4; ++j) {
    const float2 f = __half22float2(hp[j]);
    hf[2 * j] = f.x; hf[2 * j + 1] = f.y;
  }
  *(floatx4*)(hout + i)     = floatx4{hf[0], hf[1], hf[2], hf[3]};
  *(floatx4*)(hout + i + 4) = floatx4{hf[4], hf[5], hf[6], hf[7]};
  if (i >= BD) {                                           // block-uniform (BD = 8 blocks)
    float o[8];
#pragma unroll
    for (int j = 0; j < 8; ++j) {
      const float s = __builtin_amdgcn_rcpf(1.f + __builtin_amdgcn_exp2f(-LOG2E * hf[j]));
      o[j] = hf[j] * hf[j] * s;                            // h * silu(h)
    }
    *(floatx4*)(outs + i - BD)     = floatx4{o[0], o[1], o[2], o[3]};
    *(floatx4*)(outs + i - BD + 4) = floatx4{o[4], o[5], o[6], o[7]};
  }
}

extern "C" void kernel_launch(void* const* d_in, const int* in_sizes, int n_in,
                              void* d_out, int out_size, void* d_ws, size_t ws_size,
                              hipStream_t stream) {
  const float* x       = (const float*)d_in[0];
  const float* W_alpha = (const float*)d_in[1];
  const float* b_alpha = (const float*)d_in[2];
  const float* d_g     = (const float*)d_in[3];
  const float* b_g     = (const float*)d_in[4];
  const float* W_x     = (const float*)d_in[5];
  const float* b_v     = (const float*)d_in[6];
  float* out = (float*)d_out;

  // ws layout: xb (64MB) | wb (4MB) | pairbuf (128MB). h_half (67.1MB) ALIASES
  // xb+wb (68MB) — xb/wb are dead after gemm_act_k, scan_k writes h_half after.
  char* ws = (char*)d_ws;
  short*  xb      = (short*)ws;                                  // [32768][1024] bf16
  short*  wb      = (short*)(ws + (size_t)67108864);             // [2048][1024] bf16
  __half* pairbuf = (__half*)(ws + (size_t)71303168);            // [32768][1024][2] fp16
  __half* h_half  = (__half*)ws;                                 // [2049][16384] fp16

  cast_bf16_k<<<M_TOT * K_TOT / (8 * 256), 256, 0, stream>>>(x, xb);
  cast_bf16_k<<<D_DIM * K_TOT / (8 * 256), 256, 0, stream>>>(W_alpha, wb);
  cast_bf16_k<<<D_DIM * K_TOT / (8 * 256), 256, 0, stream>>>(W_x, wb + (size_t)D_DIM * K_TOT);
  gemm_act_k<<<dim3(N_TOT / 256, M_TOT / 256), 512, 0, stream>>>(xb, wb, b_alpha, b_v, pairbuf);
  scan_k<<<BD / 64, 64, 0, stream>>>((const __half2*)pairbuf, d_g, b_g, h_half);
  silu_k<<<(T_DIM + 1) * BD / (8 * 256), 256, 0, stream>>>(h_half, out);
}